// Round 1
// baseline (145.924 us; speedup 1.0000x reference)
//
#include <hip/hip_runtime.h>
#include <hip/hip_fp16.h>

#define MAIN_BLOCKS 4096
#define BLOCK 256

// Build packed per-atom record: (x, y, z, pack[sigma_f16 | sqrt(eps)_f16])
__global__ void lj_prep_kernel(const float* __restrict__ coords,
                               const float* __restrict__ sigma,
                               const float* __restrict__ eps,
                               float4* __restrict__ table, int n_atoms) {
    int i = blockIdx.x * blockDim.x + threadIdx.x;
    if (i < n_atoms) {
        float x = coords[3 * i + 0];
        float y = coords[3 * i + 1];
        float z = coords[3 * i + 2];
        float s  = sigma[i];
        float se = sqrtf(eps[i]);
        unsigned pack = (unsigned)__half_as_ushort(__float2half(s)) |
                        ((unsigned)__half_as_ushort(__float2half(se)) << 16);
        table[i] = make_float4(x, y, z, __uint_as_float(pack));
    }
}

__global__ void lj_main_kernel(const int2* __restrict__ pairs,
                               const float4* __restrict__ table,
                               const float* __restrict__ box,
                               const int* __restrict__ cutoff,
                               float* __restrict__ partials,
                               int n_pairs) {
    const float L0 = box[0], L1 = box[4], L2 = box[8];
    const float b0 = 1.0f / L0, b1 = 1.0f / L1, b2 = 1.0f / L2;
    const float c  = (float)cutoff[0];
    const float c2 = c * c;

    float acc = 0.0f;
    int tid = blockIdx.x * blockDim.x + threadIdx.x;
    int stride = gridDim.x * blockDim.x;
    for (int p = tid; p < n_pairs; p += stride) {
        int2 ij = pairs[p];
        float4 pi = table[ij.x];
        float4 pj = table[ij.y];
        float dx = pi.x - pj.x;
        float dy = pi.y - pj.y;
        float dz = pi.z - pj.z;
        // minimum image (mirrors reference: ds = dr*binv; ds -= floor(ds+0.5); dr = ds*L)
        float sx = dx * b0; sx -= floorf(sx + 0.5f); dx = sx * L0;
        float sy = dy * b1; sy -= floorf(sy + 0.5f); dy = sy * L1;
        float sz = dz * b2; sz -= floorf(sz + 0.5f); dz = sz * L2;
        float r2 = dx * dx + dy * dy + dz * dz;

        unsigned packi = __float_as_uint(pi.w);
        unsigned packj = __float_as_uint(pj.w);
        float si  = __half2float(__ushort_as_half((unsigned short)(packi & 0xffffu)));
        float sj  = __half2float(__ushort_as_half((unsigned short)(packj & 0xffffu)));
        float sei = __half2float(__ushort_as_half((unsigned short)(packi >> 16)));
        float sej = __half2float(__ushort_as_half((unsigned short)(packj >> 16)));

        float sij   = (si + sj) * 0.5f;
        float epsij = sei * sej;        // sqrt(eps_i)*sqrt(eps_j) == sqrt(eps_i*eps_j)
        float ratio = (sij * sij) / r2; // (sigma_ij/dr)^2
        float t     = ratio * ratio * ratio;  // (sigma_ij/dr)^6
        float e     = 4.0f * epsij * t * (t - 1.0f);
        acc += (r2 <= c2) ? e : 0.0f;
    }

    // wave (64-lane) reduction
    for (int off = 32; off > 0; off >>= 1)
        acc += __shfl_down(acc, off, 64);

    __shared__ float wsum[BLOCK / 64];
    int lane = threadIdx.x & 63;
    int wid  = threadIdx.x >> 6;
    if (lane == 0) wsum[wid] = acc;
    __syncthreads();
    if (threadIdx.x == 0) {
        float s = 0.0f;
        for (int w = 0; w < BLOCK / 64; w++) s += wsum[w];
        partials[blockIdx.x] = s;
    }
}

__global__ void lj_reduce_kernel(const float* __restrict__ partials, int n,
                                 float* __restrict__ out) {
    float acc = 0.0f;
    for (int i = threadIdx.x; i < n; i += blockDim.x) acc += partials[i];
    for (int off = 32; off > 0; off >>= 1)
        acc += __shfl_down(acc, off, 64);
    __shared__ float wsum[16];
    int lane = threadIdx.x & 63;
    int wid  = threadIdx.x >> 6;
    if (lane == 0) wsum[wid] = acc;
    __syncthreads();
    if (threadIdx.x == 0) {
        float s = 0.0f;
        int nw = blockDim.x / 64;
        for (int w = 0; w < nw; w++) s += wsum[w];
        out[0] = s;
    }
}

// Fallback (tiny ws): gather raw arrays, atomicAdd per block into d_out.
__global__ void lj_fallback_kernel(const float* __restrict__ coords,
                                   const int2* __restrict__ pairs,
                                   const float* __restrict__ box,
                                   const float* __restrict__ sigma,
                                   const float* __restrict__ eps,
                                   const int* __restrict__ cutoff,
                                   float* __restrict__ out, int n_pairs) {
    const float L0 = box[0], L1 = box[4], L2 = box[8];
    const float b0 = 1.0f / L0, b1 = 1.0f / L1, b2 = 1.0f / L2;
    const float c  = (float)cutoff[0];
    const float c2 = c * c;

    float acc = 0.0f;
    int tid = blockIdx.x * blockDim.x + threadIdx.x;
    int stride = gridDim.x * blockDim.x;
    for (int p = tid; p < n_pairs; p += stride) {
        int2 ij = pairs[p];
        int i = ij.x, j = ij.y;
        float dx = coords[3 * i + 0] - coords[3 * j + 0];
        float dy = coords[3 * i + 1] - coords[3 * j + 1];
        float dz = coords[3 * i + 2] - coords[3 * j + 2];
        float sx = dx * b0; sx -= floorf(sx + 0.5f); dx = sx * L0;
        float sy = dy * b1; sy -= floorf(sy + 0.5f); dy = sy * L1;
        float sz = dz * b2; sz -= floorf(sz + 0.5f); dz = sz * L2;
        float r2 = dx * dx + dy * dy + dz * dz;
        float sij   = (sigma[i] + sigma[j]) * 0.5f;
        float epsij = sqrtf(eps[i] * eps[j]);
        float ratio = (sij * sij) / r2;
        float t     = ratio * ratio * ratio;
        float e     = 4.0f * epsij * t * (t - 1.0f);
        acc += (r2 <= c2) ? e : 0.0f;
    }
    for (int off = 32; off > 0; off >>= 1)
        acc += __shfl_down(acc, off, 64);
    __shared__ float wsum[BLOCK / 64];
    int lane = threadIdx.x & 63;
    int wid  = threadIdx.x >> 6;
    if (lane == 0) wsum[wid] = acc;
    __syncthreads();
    if (threadIdx.x == 0) {
        float s = 0.0f;
        for (int w = 0; w < BLOCK / 64; w++) s += wsum[w];
        atomicAdd(out, s);
    }
}

extern "C" void kernel_launch(void* const* d_in, const int* in_sizes, int n_in,
                              void* d_out, int out_size, void* d_ws, size_t ws_size,
                              hipStream_t stream) {
    const float* coords = (const float*)d_in[0];
    const int2*  pairs  = (const int2*)d_in[1];
    const float* box    = (const float*)d_in[2];
    const float* sigma  = (const float*)d_in[3];
    const float* eps    = (const float*)d_in[4];
    const int*   cutoff = (const int*)d_in[5];
    int n_atoms = in_sizes[0] / 3;
    int n_pairs = in_sizes[1] / 2;
    float* out = (float*)d_out;

    size_t table_bytes = (size_t)n_atoms * sizeof(float4);
    size_t need = table_bytes + (size_t)MAIN_BLOCKS * sizeof(float);

    if (ws_size >= need) {
        float4* table   = (float4*)d_ws;
        float* partials = (float*)((char*)d_ws + table_bytes);
        lj_prep_kernel<<<(n_atoms + 255) / 256, 256, 0, stream>>>(
            coords, sigma, eps, table, n_atoms);
        lj_main_kernel<<<MAIN_BLOCKS, BLOCK, 0, stream>>>(
            pairs, table, box, cutoff, partials, n_pairs);
        lj_reduce_kernel<<<1, 1024, 0, stream>>>(partials, MAIN_BLOCKS, out);
    } else {
        hipMemsetAsync(d_out, 0, sizeof(float), stream);
        lj_fallback_kernel<<<MAIN_BLOCKS, BLOCK, 0, stream>>>(
            coords, pairs, box, sigma, eps, cutoff, out, n_pairs);
    }
}